// Round 9
// baseline (147.364 us; speedup 1.0000x reference)
//
#include <hip/hip_runtime.h>
#include <hip/hip_bf16.h>

// ConvSelfAttn: B=8, N=4096, C=64, d=8. FP32 I/O.
// R22: attn is MLP x traffic bound (Little's law: ~80KB in flight/CU at
// ~300cy -> ~16TB/s effective L2 rate; kernel moves ~640MB of K/V frags
// because V is re-read per 32-query tile). Fix = cut traffic 4x: waves in a
// block now share KEYS (no key-split) and own different QUERIES (128q/block);
// V/K frag tiles staged once per block into LDS via global_load_lds (linear
// dest = existing frag layout), double-buffered, one barrier/iter. Key-split
// epilogue (Obuf/Ls) deleted. Grid 8x32=256 = 1 block/CU, 64 key-iters of the
// R16 compute body. Tripwires: WRITE~8.2MB (no spill), conflicts ~0.

#define BB 8
#define NN 4096
#define CC 64
#define PSTRIDE 72
#define LOG2E 1.44269504088896f

typedef _Float16 f16;
typedef _Float16 half8 __attribute__((ext_vector_type(8)));
typedef _Float16 half4 __attribute__((ext_vector_type(4)));
typedef __fp16 fp16x2 __attribute__((ext_vector_type(2)));
typedef float floatx4 __attribute__((ext_vector_type(4)));

#define GLD16(gsrc, ldst) \
    __builtin_amdgcn_global_load_lds( \
        (const __attribute__((address_space(1))) void*)(gsrc), \
        (__attribute__((address_space(3))) void*)(ldst), 16, 0, 0)

static __device__ inline half4 pack4(float a, float b, float c, float d) {
    fp16x2 lo = __builtin_amdgcn_cvt_pkrtz(a, b);
    fp16x2 hi = __builtin_amdgcn_cvt_pkrtz(c, d);
    unsigned int lou = __builtin_bit_cast(unsigned int, lo);
    unsigned int hiu = __builtin_bit_cast(unsigned int, hi);
    unsigned long long packed = (unsigned long long)lou | ((unsigned long long)hiu << 32);
    return __builtin_bit_cast(half4, packed);
}

// ws layouts (halfs):
//   Qh [B*N][8]                          Q pre-scaled by log2e
//   Kf [B][128 pair][64 lane][8]         pair-interleaved QK A-frags; halfs
//                                        0-3 = even 16-key tile, 4-7 = odd;
//                                        quad2 = {1,0,0,0} (mf), quad3 = 0
//   Vf [B][128 pair][4 ct][64 lane][8]   16x16x16 PV A-frags; halfs 0-3 =
//                                        even 16-key tile (V[32p+4q+j][c]),
//                                        4-7 = odd tile (V[32p+16+4q+j][c])
//   qn2 [B*N] f32 | (kn2 slot unused) | Mk2 [B] f32 (atomicMax accumulator)

// ---------------- fused projection + fragment repack + norms + key-max ----------------
// grid 512 x 256 (4 waves x 16 pixels; block = 64 pixels of one batch)
__global__ __launch_bounds__(256) void proj_all_kernel(
    const float* __restrict__ x,
    const float* __restrict__ wq, const float* __restrict__ bq,
    const float* __restrict__ wk, const float* __restrict__ bk,
    const float* __restrict__ wv, const float* __restrict__ bv,
    f16* __restrict__ Qh, f16* __restrict__ Kf, f16* __restrict__ Vf,
    float* __restrict__ qn2, float* __restrict__ Mk2)
{
    __shared__ alignas(16) f16 Ws[80][PSTRIDE];  // rows 0-63=V, 64-71=Q, 72-79=K
    __shared__ float Bs[80];
    __shared__ alignas(16) f16 Vst[64][68];      // TRANSPOSED: [ch][pixel], pitch 68
    __shared__ alignas(16) f16 Ks[64][12];       // [pixel][ch]
    __shared__ float redK[4];
    const int tid = threadIdx.x;

    // weight staging, float4-vectorized (wv: i = cin*64+cout)
    for (int i4 = tid; i4 < 1024; i4 += 256) {   // 4 iters
        const int i = i4 * 4;
        const int cin = i >> 6, cout = i & 63;   // 4 consecutive couts, same cin
        const float4 w = *(const float4*)(wv + i);
        Ws[cout + 0][cin] = (f16)w.x;
        Ws[cout + 1][cin] = (f16)w.y;
        Ws[cout + 2][cin] = (f16)w.z;
        Ws[cout + 3][cin] = (f16)w.w;
    }
    if (tid < 128) {                              // wq/wk: i = cin*8+c
        const int i = tid * 4;
        const int cin = i >> 3, c = i & 7;        // c in {0,4}
        const float4 a = *(const float4*)(wq + i);
        const float4 k = *(const float4*)(wk + i);
        Ws[64 + c + 0][cin] = (f16)(a.x * LOG2E);
        Ws[64 + c + 1][cin] = (f16)(a.y * LOG2E);
        Ws[64 + c + 2][cin] = (f16)(a.z * LOG2E);
        Ws[64 + c + 3][cin] = (f16)(a.w * LOG2E);
        Ws[72 + c + 0][cin] = (f16)k.x;
        Ws[72 + c + 1][cin] = (f16)k.y;
        Ws[72 + c + 2][cin] = (f16)k.z;
        Ws[72 + c + 3][cin] = (f16)k.w;
    }
    if (tid < 80)
        Bs[tid] = (tid < 64) ? bv[tid]
                : (tid < 72 ? bq[tid - 64] * LOG2E : bk[tid - 72]);
    __syncthreads();

    const int wave = tid >> 6, lane = tid & 63;
    const int quad = lane >> 4, n16 = lane & 15;
    const long pb = (long)blockIdx.x * 64;
    const long p0 = pb + wave * 16;
    const int  b   = (int)(pb >> 12);
    const int  nnb = (int)(pb & 4095);

    half8 ax[2];
#pragma unroll
    for (int kh = 0; kh < 2; ++kh) {
        const float* xp = x + (p0 + n16) * 64 + kh * 32 + quad * 8;
        float4 x1 = *(const float4*)xp;
        float4 x2 = *(const float4*)(xp + 4);
        ax[kh][0] = (f16)x1.x; ax[kh][1] = (f16)x1.y;
        ax[kh][2] = (f16)x1.z; ax[kh][3] = (f16)x1.w;
        ax[kh][4] = (f16)x2.x; ax[kh][5] = (f16)x2.y;
        ax[kh][6] = (f16)x2.z; ax[kh][7] = (f16)x2.w;
    }

#pragma unroll
    for (int ct = 0; ct < 5; ++ct) {
        const int cout = (ct < 4) ? ct * 16 + n16 : 64 + n16;
        const float bias = Bs[cout];
        half8 b0 = *(const half8*)(&Ws[cout][quad * 8]);
        half8 b1 = *(const half8*)(&Ws[cout][32 + quad * 8]);
        floatx4 acc = {bias, bias, bias, bias};
        acc = __builtin_amdgcn_mfma_f32_16x16x32_f16(ax[0], b0, acc, 0, 0, 0);
        acc = __builtin_amdgcn_mfma_f32_16x16x32_f16(ax[1], b1, acc, 0, 0, 0);
        if (ct < 4) {
            // transposed store: one half4 of 4 consecutive pixels
            half4 vp = {(f16)acc[0], (f16)acc[1], (f16)acc[2], (f16)acc[3]};
            *(half4*)(&Vst[ct * 16 + n16][wave * 16 + quad * 4]) = vp;
        } else {
            float n2[4];
#pragma unroll
            for (int r = 0; r < 4; ++r) n2[r] = acc[r] * acc[r];
#pragma unroll
            for (int d = 1; d < 8; d <<= 1)
#pragma unroll
                for (int r = 0; r < 4; ++r) n2[r] += __shfl_xor(n2[r], d, 64);
            if (n16 == 0) {
#pragma unroll
                for (int r = 0; r < 4; ++r) qn2[p0 + quad * 4 + r] = n2[r];
            }
            // fused per-batch key max: lanes n16>=8 hold kn2 sums
            float km = fmaxf(fmaxf(n2[0], n2[1]), fmaxf(n2[2], n2[3]));
            km = fmaxf(km, __shfl_xor(km, 16, 64));
            km = fmaxf(km, __shfl_xor(km, 32, 64));
            if (n16 == 8) redK[wave] = km;
            if (n16 < 8) {
                f16* dst = Qh + (p0 + quad * 4) * 8 + n16;
#pragma unroll
                for (int r = 0; r < 4; ++r) dst[r * 8] = (f16)acc[r];
            } else {
#pragma unroll
                for (int r = 0; r < 4; ++r)
                    Ks[wave * 16 + quad * 4 + r][n16 - 8] = (f16)acc[r];
            }
        }
    }
    __syncthreads();

    // one atomicMax per block (f32 >= 0: uint-bit order == float order)
    if (tid == 0) {
        float m = fmaxf(fmaxf(redK[0], redK[1]), fmaxf(redK[2], redK[3]));
        atomicMax((unsigned int*)&Mk2[b], __float_as_uint(m));
    }

    // V fragment stores (2 tiles per wave): gather = two half4 reads from Vst
#pragma unroll
    for (int u = 0; u < 2; ++u) {
        const int tt = wave * 2 + u;
        const int kb = tt >> 2, ct = tt & 3;
        half4 lo = *(const half4*)(&Vst[ct * 16 + n16][kb * 32 + quad * 4]);
        half4 hi = *(const half4*)(&Vst[ct * 16 + n16][kb * 32 + 16 + quad * 4]);
        half8 v = {lo[0], lo[1], lo[2], lo[3], hi[0], hi[1], hi[2], hi[3]};
        const size_t kbg = (size_t)b * 128 + (nnb >> 5) + kb;
        *(half8*)(Vf + (kbg * 4 + ct) * 512 + lane * 8) = v;
    }
    // K pair-tile stores: waves 0-1 each store one pair as full 16B/lane lines
    if (wave < 2) {
        half8 kp = {0, 0, 0, 0, 0, 0, 0, 0};
#pragma unroll
        for (int e = 0; e < 2; ++e) {
            const int t = wave * 2 + e;
            if (quad < 2) {
                half4 kd = *(const half4*)(&Ks[t * 16 + n16][quad * 4]);
                kp[e * 4 + 0] = kd[0]; kp[e * 4 + 1] = kd[1];
                kp[e * 4 + 2] = kd[2]; kp[e * 4 + 3] = kd[3];
            } else if (quad == 2) {
                kp[e * 4 + 0] = (f16)1.f;  // mf ones channel
            }
        }
        const size_t kpg = (size_t)b * 128 + (nnb >> 5) + wave;
        *(half8*)(Kf + kpg * 512 + lane * 8) = kp;
    }
}

// ---------------- flash attention, static-max, q-split block, shared-key LDS ----------------
// grid B*32 = 256 x 256 thr (1 block/CU). Block = 128 queries of one batch;
// wave w owns queries [qb*128 + w*32, +32). All waves iterate ALL 4096 keys
// (64 iters of 64 keys); V/K frag tiles staged once per block into LDS
// (global_load_lds, linear layout, double-buffered, 1 barrier/iter) and
// shared by the 4 waves -> K/V L2 traffic / 4. No key-split -> no Obuf/Ls
// combine; each wave writes its queries directly.
__global__ __launch_bounds__(256, 1) void attn_kernel(
    const f16* __restrict__ Qh, const f16* __restrict__ Kf,
    const f16* __restrict__ Vf,
    const float* __restrict__ qn2, const float* __restrict__ Mk2,
    const float* __restrict__ x, const float* __restrict__ gptr,
    float* __restrict__ out)
{
    // chunks 0-7 = V (p*4+ct), 8-9 = K (pair 0/1); 2 buffers, 20KB total
    __shared__ alignas(16) f16 KVb[2][10][512];

    const int tid  = threadIdx.x;
    const int wave = tid >> 6, lane = tid & 63;
    const int quad = lane >> 4, n16 = lane & 15;

    const int b  = blockIdx.x & 7;
    const int qb = blockIdx.x >> 3;               // 0..31 (128-query block)
    const size_t bN = (size_t)b * NN;

    const float mk2 = Mk2[b];

    // Q B-frags: quads 0-1 = Q data; quad2 = {-mf,0,0,0}; quad3 = 0.
    half4 bq4[2];
#pragma unroll
    for (int qt2 = 0; qt2 < 2; ++qt2) {
        const int q = qb * 128 + wave * 32 + qt2 * 16 + n16;
        const float mf = __builtin_sqrtf(qn2[bN + q] * mk2) - 12.0f;
        half4 v = {0, 0, 0, 0};
        if (quad < 2)
            v = *(const half4*)(Qh + (bN + q) * 8 + quad * 4);
        else if (quad == 2)
            v[0] = (f16)(-mf);
        bq4[qt2] = v;
    }

    floatx4 oacc[2][4];
#pragma unroll
    for (int qt2 = 0; qt2 < 2; ++qt2)
#pragma unroll
        for (int ct = 0; ct < 4; ++ct) oacc[qt2][ct] = (floatx4){0.f, 0.f, 0.f, 0.f};
    float l_loc[2] = {0.f, 0.f};

    const f16* kfb = Kf + (size_t)b * 128 * 512;
    const f16* vfb = Vf + (size_t)b * 128 * 2048;
    const floatx4 zero4 = {0.f, 0.f, 0.f, 0.f};
    const int lo8 = lane * 8;

    // stage 64-key tile `it` (pairs 2it, 2it+1) into buffer bufi
    auto stage = [&](int bufi, int it) {
        const size_t pr = (size_t)it * 2;
        const f16* vs = vfb + pr * 2048 + lo8;   // + (p*4+ct)*512
        const f16* ks = kfb + pr * 512 + lo8;    // + pair*512
        f16 (*L)[512] = KVb[bufi];
        if (wave == 0) {
            GLD16(vs + 0 * 512, &L[0][0]);
            GLD16(vs + 1 * 512, &L[1][0]);
            GLD16(ks,           &L[8][0]);
        } else if (wave == 1) {
            GLD16(vs + 2 * 512, &L[2][0]);
            GLD16(vs + 3 * 512, &L[3][0]);
            GLD16(ks + 512,     &L[9][0]);
        } else if (wave == 2) {
            GLD16(vs + 4 * 512, &L[4][0]);
            GLD16(vs + 5 * 512, &L[5][0]);
        } else {
            GLD16(vs + 6 * 512, &L[6][0]);
            GLD16(vs + 7 * 512, &L[7][0]);
        }
    };

    stage(0, 0);

    for (int it = 0; it < 64; ++it) {
        __syncthreads();                 // buf[it&1] staged; prev reads done
        if (it < 63) stage((it + 1) & 1, it + 1);

        const f16 (*L)[512] = KVb[it & 1];
        half8 kk0 = *(const half8*)(&L[8][lo8]);
        half8 kk1 = *(const half8*)(&L[9][lo8]);
        half8 avp[2][4];
#pragma unroll
        for (int p = 0; p < 2; ++p)
#pragma unroll
            for (int ct = 0; ct < 4; ++ct)
                avp[p][ct] = *(const half8*)(&L[p * 4 + ct][lo8]);

        half4 ak[4];
        ak[0] = __builtin_shufflevector(kk0, kk0, 0, 1, 2, 3);
        ak[1] = __builtin_shufflevector(kk0, kk0, 4, 5, 6, 7);
        ak[2] = __builtin_shufflevector(kk1, kk1, 0, 1, 2, 3);
        ak[3] = __builtin_shufflevector(kk1, kk1, 4, 5, 6, 7);

#pragma unroll
        for (int qt2 = 0; qt2 < 2; ++qt2) {
            floatx4 sf[4];
#pragma unroll
            for (int t = 0; t < 4; ++t)
                sf[t] = __builtin_amdgcn_mfma_f32_16x16x16f16(ak[t], bq4[qt2], zero4, 0, 0, 0);

            half4 pk[4];
            float rst[4];
#pragma unroll
            for (int t = 0; t < 4; ++t) {
                float p0 = __builtin_exp2f(sf[t][0]);
                float p1 = __builtin_exp2f(sf[t][1]);
                float p2 = __builtin_exp2f(sf[t][2]);
                float p3 = __builtin_exp2f(sf[t][3]);
                rst[t] = (p0 + p1) + (p2 + p3);
                pk[t] = pack4(p0, p1, p2, p3);
            }
            l_loc[qt2] += (rst[0] + rst[1]) + (rst[2] + rst[3]);

            // PV: 16x16x16, A = V tile frag (even/odd half of pair), B = pk[t]
#pragma unroll
            for (int t = 0; t < 4; ++t) {
                const int p = t >> 1;
#pragma unroll
                for (int ct = 0; ct < 4; ++ct) {
                    half4 va = (t & 1)
                        ? __builtin_shufflevector(avp[p][ct], avp[p][ct], 4, 5, 6, 7)
                        : __builtin_shufflevector(avp[p][ct], avp[p][ct], 0, 1, 2, 3);
                    oacc[qt2][ct] = __builtin_amdgcn_mfma_f32_16x16x16f16(va, pk[t], oacc[qt2][ct], 0, 0, 0);
                }
            }
        }
    }

    // epilogue: no cross-wave combine — each wave owns its 32 queries fully
    const float g = gptr[0];
#pragma unroll
    for (int qt2 = 0; qt2 < 2; ++qt2) {
        float l = l_loc[qt2];
        l += __shfl_xor(l, 16, 64);
        l += __shfl_xor(l, 32, 64);
        const float scale = g / l;
        const int q = qb * 128 + wave * 32 + qt2 * 16 + n16;
#pragma unroll
        for (int ct = 0; ct < 4; ++ct) {
            const size_t idx = (bN + q) * CC + ct * 16 + quad * 4;
            float4 xr = *(const float4*)(x + idx);
            float4 res;
            res.x = oacc[qt2][ct][0] * scale + xr.x;
            res.y = oacc[qt2][ct][1] * scale + xr.y;
            res.z = oacc[qt2][ct][2] * scale + xr.z;
            res.w = oacc[qt2][ct][3] * scale + xr.w;
            *(float4*)(out + idx) = res;
        }
    }
}

extern "C" void kernel_launch(void* const* d_in, const int* in_sizes, int n_in,
                              void* d_out, int out_size, void* d_ws, size_t ws_size,
                              hipStream_t stream) {
    const float* x     = (const float*)d_in[0];
    const float* wq    = (const float*)d_in[1];
    const float* bq    = (const float*)d_in[2];
    const float* wk    = (const float*)d_in[3];
    const float* bk    = (const float*)d_in[4];
    const float* wv    = (const float*)d_in[5];
    const float* bv    = (const float*)d_in[6];
    const float* gamma = (const float*)d_in[7];
    float* out = (float*)d_out;

    // ws: Qh 512KB | Kf 1MB | Vf 4MB | qn2 128KB | (kn2 slot unused) | Mk2
    f16* Qh = (f16*)d_ws;
    f16* Kf = Qh + (size_t)BB * NN * 8;
    f16* Vf = Kf + (size_t)BB * 128 * 512;
    float* qn2 = (float*)(Vf + (size_t)BB * 128 * 4 * 512);
    float* kn2 = qn2 + (size_t)BB * NN;   // unused, address layout kept
    float* Mk2 = kn2 + (size_t)BB * NN;

    hipMemsetAsync(Mk2, 0, BB * sizeof(float), stream);
    proj_all_kernel<<<512, 256, 0, stream>>>(x, wq, bq, wk, bk, wv, bv,
                                             Qh, Kf, Vf, qn2, Mk2);
    attn_kernel<<<BB * 32, 256, 0, stream>>>(Qh, Kf, Vf, qn2, Mk2, x, gamma, out);
}

// Round 10
// 122.383 us; speedup vs baseline: 1.2041x; 1.2041x over previous
//
#include <hip/hip_runtime.h>
#include <hip/hip_bf16.h>

// ConvSelfAttn: B=8, N=4096, C=64, d=8. FP32 I/O.
// R23: R22 (LDS-shared KV, 1 blk/CU) refuted the traffic theory: 1/4 traffic,
// -41% perf -> attn is latency-structural; R16 form stands. Ledger: traffic x,
// TLP x, ILP x, pipeline x. Two remaining proven/cheap levers applied to the
// R16/R21 best (attn body otherwise IDENTICAL to R16):
//  (a) s_setprio(1) around the per-iter compute cluster (T5: +4-7% measured
//      on attn with independent waves — R16's K-loop has no barriers);
//  (b) hipMemsetAsync dispatch deleted: proj writes per-BLOCK key-max slots
//      (plain store, no init), attn fmax-reduces its batch's 64 slots once.
// Tripwires: attn VGPR~84 / LDS 31232 / conflicts 0 / WRITE~8.2MB unchanged.

#define BB 8
#define NN 4096
#define CC 64
#define PSTRIDE 72
#define LOG2E 1.44269504088896f

typedef _Float16 f16;
typedef _Float16 half8 __attribute__((ext_vector_type(8)));
typedef _Float16 half4 __attribute__((ext_vector_type(4)));
typedef __fp16 fp16x2 __attribute__((ext_vector_type(2)));
typedef float floatx4 __attribute__((ext_vector_type(4)));

static __device__ inline half4 pack4(float a, float b, float c, float d) {
    fp16x2 lo = __builtin_amdgcn_cvt_pkrtz(a, b);
    fp16x2 hi = __builtin_amdgcn_cvt_pkrtz(c, d);
    unsigned int lou = __builtin_bit_cast(unsigned int, lo);
    unsigned int hiu = __builtin_bit_cast(unsigned int, hi);
    unsigned long long packed = (unsigned long long)lou | ((unsigned long long)hiu << 32);
    return __builtin_bit_cast(half4, packed);
}

// ws layouts (halfs):
//   Qh [B*N][8]                          Q pre-scaled by log2e
//   Kf [B][128 pair][64 lane][8]         pair-interleaved QK A-frags; halfs
//                                        0-3 = even 16-key tile, 4-7 = odd;
//                                        quad2 = {1,0,0,0} (mf), quad3 = 0
//   Vf [B][128 pair][4 ct][64 lane][8]   16x16x16 PV A-frags; halfs 0-3 =
//                                        even 16-key tile (V[32p+4q+j][c]),
//                                        4-7 = odd tile (V[32p+16+4q+j][c])
//   qn2 [B*N] f32 | Mkb [512] f32 (per-proj-block key-norm max, no init)

// ---------------- fused projection + fragment repack + norms + key-max ----------------
// grid 512 x 256 (4 waves x 16 pixels; block = 64 pixels of one batch)
__global__ __launch_bounds__(256) void proj_all_kernel(
    const float* __restrict__ x,
    const float* __restrict__ wq, const float* __restrict__ bq,
    const float* __restrict__ wk, const float* __restrict__ bk,
    const float* __restrict__ wv, const float* __restrict__ bv,
    f16* __restrict__ Qh, f16* __restrict__ Kf, f16* __restrict__ Vf,
    float* __restrict__ qn2, float* __restrict__ Mkb)
{
    __shared__ alignas(16) f16 Ws[80][PSTRIDE];  // rows 0-63=V, 64-71=Q, 72-79=K
    __shared__ float Bs[80];
    __shared__ alignas(16) f16 Vst[64][68];      // TRANSPOSED: [ch][pixel], pitch 68
    __shared__ alignas(16) f16 Ks[64][12];       // [pixel][ch]
    __shared__ float redK[4];
    const int tid = threadIdx.x;

    // weight staging, float4-vectorized (wv: i = cin*64+cout)
    for (int i4 = tid; i4 < 1024; i4 += 256) {   // 4 iters
        const int i = i4 * 4;
        const int cin = i >> 6, cout = i & 63;   // 4 consecutive couts, same cin
        const float4 w = *(const float4*)(wv + i);
        Ws[cout + 0][cin] = (f16)w.x;
        Ws[cout + 1][cin] = (f16)w.y;
        Ws[cout + 2][cin] = (f16)w.z;
        Ws[cout + 3][cin] = (f16)w.w;
    }
    if (tid < 128) {                              // wq/wk: i = cin*8+c
        const int i = tid * 4;
        const int cin = i >> 3, c = i & 7;        // c in {0,4}
        const float4 a = *(const float4*)(wq + i);
        const float4 k = *(const float4*)(wk + i);
        Ws[64 + c + 0][cin] = (f16)(a.x * LOG2E);
        Ws[64 + c + 1][cin] = (f16)(a.y * LOG2E);
        Ws[64 + c + 2][cin] = (f16)(a.z * LOG2E);
        Ws[64 + c + 3][cin] = (f16)(a.w * LOG2E);
        Ws[72 + c + 0][cin] = (f16)k.x;
        Ws[72 + c + 1][cin] = (f16)k.y;
        Ws[72 + c + 2][cin] = (f16)k.z;
        Ws[72 + c + 3][cin] = (f16)k.w;
    }
    if (tid < 80)
        Bs[tid] = (tid < 64) ? bv[tid]
                : (tid < 72 ? bq[tid - 64] * LOG2E : bk[tid - 72]);
    __syncthreads();

    const int wave = tid >> 6, lane = tid & 63;
    const int quad = lane >> 4, n16 = lane & 15;
    const long pb = (long)blockIdx.x * 64;
    const long p0 = pb + wave * 16;
    const int  b   = (int)(pb >> 12);
    const int  nnb = (int)(pb & 4095);

    half8 ax[2];
#pragma unroll
    for (int kh = 0; kh < 2; ++kh) {
        const float* xp = x + (p0 + n16) * 64 + kh * 32 + quad * 8;
        float4 x1 = *(const float4*)xp;
        float4 x2 = *(const float4*)(xp + 4);
        ax[kh][0] = (f16)x1.x; ax[kh][1] = (f16)x1.y;
        ax[kh][2] = (f16)x1.z; ax[kh][3] = (f16)x1.w;
        ax[kh][4] = (f16)x2.x; ax[kh][5] = (f16)x2.y;
        ax[kh][6] = (f16)x2.z; ax[kh][7] = (f16)x2.w;
    }

#pragma unroll
    for (int ct = 0; ct < 5; ++ct) {
        const int cout = (ct < 4) ? ct * 16 + n16 : 64 + n16;
        const float bias = Bs[cout];
        half8 b0 = *(const half8*)(&Ws[cout][quad * 8]);
        half8 b1 = *(const half8*)(&Ws[cout][32 + quad * 8]);
        floatx4 acc = {bias, bias, bias, bias};
        acc = __builtin_amdgcn_mfma_f32_16x16x32_f16(ax[0], b0, acc, 0, 0, 0);
        acc = __builtin_amdgcn_mfma_f32_16x16x32_f16(ax[1], b1, acc, 0, 0, 0);
        if (ct < 4) {
            // transposed store: one half4 of 4 consecutive pixels
            half4 vp = {(f16)acc[0], (f16)acc[1], (f16)acc[2], (f16)acc[3]};
            *(half4*)(&Vst[ct * 16 + n16][wave * 16 + quad * 4]) = vp;
        } else {
            float n2[4];
#pragma unroll
            for (int r = 0; r < 4; ++r) n2[r] = acc[r] * acc[r];
#pragma unroll
            for (int d = 1; d < 8; d <<= 1)
#pragma unroll
                for (int r = 0; r < 4; ++r) n2[r] += __shfl_xor(n2[r], d, 64);
            if (n16 == 0) {
#pragma unroll
                for (int r = 0; r < 4; ++r) qn2[p0 + quad * 4 + r] = n2[r];
            }
            // fused per-batch key max: lanes n16>=8 hold kn2 sums
            float km = fmaxf(fmaxf(n2[0], n2[1]), fmaxf(n2[2], n2[3]));
            km = fmaxf(km, __shfl_xor(km, 16, 64));
            km = fmaxf(km, __shfl_xor(km, 32, 64));
            if (n16 == 8) redK[wave] = km;
            if (n16 < 8) {
                f16* dst = Qh + (p0 + quad * 4) * 8 + n16;
#pragma unroll
                for (int r = 0; r < 4; ++r) dst[r * 8] = (f16)acc[r];
            } else {
#pragma unroll
                for (int r = 0; r < 4; ++r)
                    Ks[wave * 16 + quad * 4 + r][n16 - 8] = (f16)acc[r];
            }
        }
    }
    __syncthreads();

    // per-block key-max slot (plain store — no init dispatch needed)
    if (tid == 0) {
        float m = fmaxf(fmaxf(redK[0], redK[1]), fmaxf(redK[2], redK[3]));
        Mkb[blockIdx.x] = m;
    }

    // V fragment stores (2 tiles per wave): gather = two half4 reads from Vst
#pragma unroll
    for (int u = 0; u < 2; ++u) {
        const int tt = wave * 2 + u;
        const int kb = tt >> 2, ct = tt & 3;
        half4 lo = *(const half4*)(&Vst[ct * 16 + n16][kb * 32 + quad * 4]);
        half4 hi = *(const half4*)(&Vst[ct * 16 + n16][kb * 32 + 16 + quad * 4]);
        half8 v = {lo[0], lo[1], lo[2], lo[3], hi[0], hi[1], hi[2], hi[3]};
        const size_t kbg = (size_t)b * 128 + (nnb >> 5) + kb;
        *(half8*)(Vf + (kbg * 4 + ct) * 512 + lane * 8) = v;
    }
    // K pair-tile stores: waves 0-1 each store one pair as full 16B/lane lines
    if (wave < 2) {
        half8 kp = {0, 0, 0, 0, 0, 0, 0, 0};
#pragma unroll
        for (int e = 0; e < 2; ++e) {
            const int t = wave * 2 + e;
            if (quad < 2) {
                half4 kd = *(const half4*)(&Ks[t * 16 + n16][quad * 4]);
                kp[e * 4 + 0] = kd[0]; kp[e * 4 + 1] = kd[1];
                kp[e * 4 + 2] = kd[2]; kp[e * 4 + 3] = kd[3];
            } else if (quad == 2) {
                kp[e * 4 + 0] = (f16)1.f;  // mf ones channel
            }
        }
        const size_t kpg = (size_t)b * 128 + (nnb >> 5) + wave;
        *(half8*)(Kf + kpg * 512 + lane * 8) = kp;
    }
}

// ---------------- flash attention, static-max, 32 q/wave, key-split 4 ----------------
// R16 body (best measured: 49.6us) + setprio(1) around the compute cluster.
// grid B*128 = 1024 x 256 thr; wave = ks (0..3): keys [ks*1024,+1024), 16
// iters of 64 keys. P never touches LDS (16x16x16 PV, B = pack4(sf)).
__global__ __launch_bounds__(256, 3) void attn_kernel(
    const f16* __restrict__ Qh, const f16* __restrict__ Kf,
    const f16* __restrict__ Vf,
    const float* __restrict__ qn2, const float* __restrict__ Mkb,
    const float* __restrict__ x, const float* __restrict__ gptr,
    float* __restrict__ out)
{
    // smem: Obuf only (f32, stride 20, 3 partial ks x 2 qt2 x 64 lanes x 16ch)
    __shared__ alignas(16) char smem[30720];
    __shared__ float Ls[4][2][16];
    float* Obuf = (float*)smem;

    const int tid  = threadIdx.x;
    const int wave = tid >> 6, lane = tid & 63;
    const int quad = lane >> 4, n16 = lane & 15;
    const int ks = wave;

    const int b  = blockIdx.x & 7;
    const int qt = blockIdx.x >> 3;               // 0..127 (32-query tile)
    const size_t bN = (size_t)b * NN;

    // per-batch key-norm max: reduce this batch's 64 per-proj-block slots
    float mk2;
    {
        float m = Mkb[b * 64 + lane];             // lanes 0..63 cover all slots
        m = fmaxf(m, __shfl_xor(m, 1, 64));
        m = fmaxf(m, __shfl_xor(m, 2, 64));
        m = fmaxf(m, __shfl_xor(m, 4, 64));
        m = fmaxf(m, __shfl_xor(m, 8, 64));
        m = fmaxf(m, __shfl_xor(m, 16, 64));
        m = fmaxf(m, __shfl_xor(m, 32, 64));
        mk2 = m;
    }

    // Q B-frags: quads 0-1 = Q data; quad2 = {-mf,0,0,0}; quad3 = 0.
    half4 bq4[2];
#pragma unroll
    for (int qt2 = 0; qt2 < 2; ++qt2) {
        const int q = qt * 32 + qt2 * 16 + n16;
        const float mf = __builtin_sqrtf(qn2[bN + q] * mk2) - 12.0f;
        half4 v = {0, 0, 0, 0};
        if (quad < 2)
            v = *(const half4*)(Qh + (bN + q) * 8 + quad * 4);
        else if (quad == 2)
            v[0] = (f16)(-mf);
        bq4[qt2] = v;
    }

    floatx4 oacc[2][4];
#pragma unroll
    for (int qt2 = 0; qt2 < 2; ++qt2)
#pragma unroll
        for (int ct = 0; ct < 4; ++ct) oacc[qt2][ct] = (floatx4){0.f, 0.f, 0.f, 0.f};
    float l_loc[2] = {0.f, 0.f};

    const f16* kfb = Kf + ((size_t)b * 128 + ks * 32) * 512 + lane * 8;
    const f16* vfb = Vf + ((size_t)b * 128 + ks * 32) * 2048 + lane * 8;
    const floatx4 zero4 = {0.f, 0.f, 0.f, 0.f};

    half8 kkc0 = *(const half8*)(kfb + 0);
    half8 kkc1 = *(const half8*)(kfb + 512);

    for (int it = 0; it < 16; ++it) {
        // V A-frag pair loads for this iteration's 64 keys (2 pairs x 4 ct)
        half8 avp[2][4];
#pragma unroll
        for (int p = 0; p < 2; ++p)
#pragma unroll
            for (int ct = 0; ct < 4; ++ct)
                avp[p][ct] = *(const half8*)(vfb + ((size_t)(it * 2 + p) * 4 + ct) * 512);

        half4 ak[4];
        ak[0] = __builtin_shufflevector(kkc0, kkc0, 0, 1, 2, 3);
        ak[1] = __builtin_shufflevector(kkc0, kkc0, 4, 5, 6, 7);
        ak[2] = __builtin_shufflevector(kkc1, kkc1, 0, 1, 2, 3);
        ak[3] = __builtin_shufflevector(kkc1, kkc1, 4, 5, 6, 7);

        // prefetch kk(it+1)
        const int itn = (it < 15) ? it + 1 : 15;
        kkc0 = *(const half8*)(kfb + (size_t)itn * 1024);
        kkc1 = *(const half8*)(kfb + (size_t)itn * 1024 + 512);

        // compute cluster: boost this wave while others issue loads (T5)
        __builtin_amdgcn_s_setprio(1);
#pragma unroll
        for (int qt2 = 0; qt2 < 2; ++qt2) {
            floatx4 sf[4];
#pragma unroll
            for (int t = 0; t < 4; ++t)
                sf[t] = __builtin_amdgcn_mfma_f32_16x16x16f16(ak[t], bq4[qt2], zero4, 0, 0, 0);

            half4 pk[4];
            float rst[4];
#pragma unroll
            for (int t = 0; t < 4; ++t) {
                float p0 = __builtin_exp2f(sf[t][0]);
                float p1 = __builtin_exp2f(sf[t][1]);
                float p2 = __builtin_exp2f(sf[t][2]);
                float p3 = __builtin_exp2f(sf[t][3]);
                rst[t] = (p0 + p1) + (p2 + p3);
                pk[t] = pack4(p0, p1, p2, p3);
            }
            l_loc[qt2] += (rst[0] + rst[1]) + (rst[2] + rst[3]);

            // PV: 16x16x16, A = V tile frag (even/odd half of pair), B = pk[t]
#pragma unroll
            for (int t = 0; t < 4; ++t) {
                const int p = t >> 1;
#pragma unroll
                for (int ct = 0; ct < 4; ++ct) {
                    half4 va = (t & 1)
                        ? __builtin_shufflevector(avp[p][ct], avp[p][ct], 4, 5, 6, 7)
                        : __builtin_shufflevector(avp[p][ct], avp[p][ct], 0, 1, 2, 3);
                    oacc[qt2][ct] = __builtin_amdgcn_mfma_f32_16x16x16f16(va, pk[t], oacc[qt2][ct], 0, 0, 0);
                }
            }
        }
        __builtin_amdgcn_s_setprio(0);
    }

    float l_run[2];
#pragma unroll
    for (int qt2 = 0; qt2 < 2; ++qt2) {
        float l = l_loc[qt2];
        l += __shfl_xor(l, 16, 64);
        l += __shfl_xor(l, 32, 64);
        l_run[qt2] = l;
    }

    __syncthreads();   // Obuf combine (f32, stride 20)
    if (ks > 0) {
#pragma unroll
        for (int qt2 = 0; qt2 < 2; ++qt2) {
            if (quad == 0) Ls[ks][qt2][n16] = l_run[qt2];
            float* ob = Obuf + (size_t)(((ks - 1) * 2 + qt2) * 64 + lane) * 20;
#pragma unroll
            for (int ct = 0; ct < 4; ++ct)
                *(floatx4*)(ob + ct * 4) = oacc[qt2][ct];
        }
    }
    __syncthreads();
    if (ks == 0) {
        const float g = gptr[0];
#pragma unroll
        for (int qt2 = 0; qt2 < 2; ++qt2) {
            float l = l_run[qt2];
            float o[16];
#pragma unroll
            for (int ct = 0; ct < 4; ++ct)
#pragma unroll
                for (int r = 0; r < 4; ++r) o[ct * 4 + r] = oacc[qt2][ct][r];
#pragma unroll
            for (int p = 1; p < 4; ++p) {
                l += Ls[p][qt2][n16];
                const float* ob = Obuf + (size_t)(((p - 1) * 2 + qt2) * 64 + lane) * 20;
#pragma unroll
                for (int ct = 0; ct < 4; ++ct) {
                    floatx4 t = *(const floatx4*)(ob + ct * 4);
                    o[ct * 4 + 0] += t[0]; o[ct * 4 + 1] += t[1];
                    o[ct * 4 + 2] += t[2]; o[ct * 4 + 3] += t[3];
                }
            }
            const float scale = g / l;
            const int q = qt * 32 + qt2 * 16 + n16;
#pragma unroll
            for (int ct = 0; ct < 4; ++ct) {
                const size_t idx = (bN + q) * CC + ct * 16 + quad * 4;
                float4 xr = *(const float4*)(x + idx);
                float4 res;
                res.x = o[ct * 4 + 0] * scale + xr.x;
                res.y = o[ct * 4 + 1] * scale + xr.y;
                res.z = o[ct * 4 + 2] * scale + xr.z;
                res.w = o[ct * 4 + 3] * scale + xr.w;
                *(float4*)(out + idx) = res;
            }
        }
    }
}

extern "C" void kernel_launch(void* const* d_in, const int* in_sizes, int n_in,
                              void* d_out, int out_size, void* d_ws, size_t ws_size,
                              hipStream_t stream) {
    const float* x     = (const float*)d_in[0];
    const float* wq    = (const float*)d_in[1];
    const float* bq    = (const float*)d_in[2];
    const float* wk    = (const float*)d_in[3];
    const float* bk    = (const float*)d_in[4];
    const float* wv    = (const float*)d_in[5];
    const float* bv    = (const float*)d_in[6];
    const float* gamma = (const float*)d_in[7];
    float* out = (float*)d_out;

    // ws: Qh 512KB | Kf 1MB | Vf 4MB | qn2 128KB | Mkb 2KB (per-block maxima)
    f16* Qh = (f16*)d_ws;
    f16* Kf = Qh + (size_t)BB * NN * 8;
    f16* Vf = Kf + (size_t)BB * 128 * 512;
    float* qn2 = (float*)(Vf + (size_t)BB * 128 * 4 * 512);
    float* Mkb = qn2 + (size_t)BB * NN;

    proj_all_kernel<<<512, 256, 0, stream>>>(x, wq, bq, wk, bk, wv, bv,
                                             Qh, Kf, Vf, qn2, Mkb);
    attn_kernel<<<BB * 128, 256, 0, stream>>>(Qh, Kf, Vf, qn2, Mkb, x, gamma, out);
}

// Round 11
// 120.373 us; speedup vs baseline: 1.2242x; 1.0167x over previous
//
#include <hip/hip_runtime.h>
#include <hip/hip_bf16.h>

// ConvSelfAttn: B=8, N=4096, C=64, d=8. FP32 I/O.
// R24: R23 split verdict — (b) Mkb slots / memset-dispatch deletion paid
// (total 122.4, session best); (a) setprio REGRESSED attn (49.6 -> 51-58us,
// high variance: our 4 waves/block interact via epilogue barrier + shared
// L1/L2 stream, unlike the 1-wave/block structure where T5 measured +4-7%).
// R24 = R23 minus setprio: attn body byte-identical to R16 (best: 49.6us),
// Mkb path kept. Ledger closed: traffic x, TLP x, ILP x, pipeline x,
// setprio x — R16's simple barrier-free form is the source-level optimum.
// Tripwires: attn 49.6 +/- 0.3 low-variance, VGPR 84, conflicts 0, WRITE 8.2MB.

#define BB 8
#define NN 4096
#define CC 64
#define PSTRIDE 72
#define LOG2E 1.44269504088896f

typedef _Float16 f16;
typedef _Float16 half8 __attribute__((ext_vector_type(8)));
typedef _Float16 half4 __attribute__((ext_vector_type(4)));
typedef __fp16 fp16x2 __attribute__((ext_vector_type(2)));
typedef float floatx4 __attribute__((ext_vector_type(4)));

static __device__ inline half4 pack4(float a, float b, float c, float d) {
    fp16x2 lo = __builtin_amdgcn_cvt_pkrtz(a, b);
    fp16x2 hi = __builtin_amdgcn_cvt_pkrtz(c, d);
    unsigned int lou = __builtin_bit_cast(unsigned int, lo);
    unsigned int hiu = __builtin_bit_cast(unsigned int, hi);
    unsigned long long packed = (unsigned long long)lou | ((unsigned long long)hiu << 32);
    return __builtin_bit_cast(half4, packed);
}

// ws layouts (halfs):
//   Qh [B*N][8]                          Q pre-scaled by log2e
//   Kf [B][128 pair][64 lane][8]         pair-interleaved QK A-frags; halfs
//                                        0-3 = even 16-key tile, 4-7 = odd;
//                                        quad2 = {1,0,0,0} (mf), quad3 = 0
//   Vf [B][128 pair][4 ct][64 lane][8]   16x16x16 PV A-frags; halfs 0-3 =
//                                        even 16-key tile (V[32p+4q+j][c]),
//                                        4-7 = odd tile (V[32p+16+4q+j][c])
//   qn2 [B*N] f32 | Mkb [512] f32 (per-proj-block key-norm max, no init)

// ---------------- fused projection + fragment repack + norms + key-max ----------------
// grid 512 x 256 (4 waves x 16 pixels; block = 64 pixels of one batch)
__global__ __launch_bounds__(256) void proj_all_kernel(
    const float* __restrict__ x,
    const float* __restrict__ wq, const float* __restrict__ bq,
    const float* __restrict__ wk, const float* __restrict__ bk,
    const float* __restrict__ wv, const float* __restrict__ bv,
    f16* __restrict__ Qh, f16* __restrict__ Kf, f16* __restrict__ Vf,
    float* __restrict__ qn2, float* __restrict__ Mkb)
{
    __shared__ alignas(16) f16 Ws[80][PSTRIDE];  // rows 0-63=V, 64-71=Q, 72-79=K
    __shared__ float Bs[80];
    __shared__ alignas(16) f16 Vst[64][68];      // TRANSPOSED: [ch][pixel], pitch 68
    __shared__ alignas(16) f16 Ks[64][12];       // [pixel][ch]
    __shared__ float redK[4];
    const int tid = threadIdx.x;

    // weight staging, float4-vectorized (wv: i = cin*64+cout)
    for (int i4 = tid; i4 < 1024; i4 += 256) {   // 4 iters
        const int i = i4 * 4;
        const int cin = i >> 6, cout = i & 63;   // 4 consecutive couts, same cin
        const float4 w = *(const float4*)(wv + i);
        Ws[cout + 0][cin] = (f16)w.x;
        Ws[cout + 1][cin] = (f16)w.y;
        Ws[cout + 2][cin] = (f16)w.z;
        Ws[cout + 3][cin] = (f16)w.w;
    }
    if (tid < 128) {                              // wq/wk: i = cin*8+c
        const int i = tid * 4;
        const int cin = i >> 3, c = i & 7;        // c in {0,4}
        const float4 a = *(const float4*)(wq + i);
        const float4 k = *(const float4*)(wk + i);
        Ws[64 + c + 0][cin] = (f16)(a.x * LOG2E);
        Ws[64 + c + 1][cin] = (f16)(a.y * LOG2E);
        Ws[64 + c + 2][cin] = (f16)(a.z * LOG2E);
        Ws[64 + c + 3][cin] = (f16)(a.w * LOG2E);
        Ws[72 + c + 0][cin] = (f16)k.x;
        Ws[72 + c + 1][cin] = (f16)k.y;
        Ws[72 + c + 2][cin] = (f16)k.z;
        Ws[72 + c + 3][cin] = (f16)k.w;
    }
    if (tid < 80)
        Bs[tid] = (tid < 64) ? bv[tid]
                : (tid < 72 ? bq[tid - 64] * LOG2E : bk[tid - 72]);
    __syncthreads();

    const int wave = tid >> 6, lane = tid & 63;
    const int quad = lane >> 4, n16 = lane & 15;
    const long pb = (long)blockIdx.x * 64;
    const long p0 = pb + wave * 16;
    const int  b   = (int)(pb >> 12);
    const int  nnb = (int)(pb & 4095);

    half8 ax[2];
#pragma unroll
    for (int kh = 0; kh < 2; ++kh) {
        const float* xp = x + (p0 + n16) * 64 + kh * 32 + quad * 8;
        float4 x1 = *(const float4*)xp;
        float4 x2 = *(const float4*)(xp + 4);
        ax[kh][0] = (f16)x1.x; ax[kh][1] = (f16)x1.y;
        ax[kh][2] = (f16)x1.z; ax[kh][3] = (f16)x1.w;
        ax[kh][4] = (f16)x2.x; ax[kh][5] = (f16)x2.y;
        ax[kh][6] = (f16)x2.z; ax[kh][7] = (f16)x2.w;
    }

#pragma unroll
    for (int ct = 0; ct < 5; ++ct) {
        const int cout = (ct < 4) ? ct * 16 + n16 : 64 + n16;
        const float bias = Bs[cout];
        half8 b0 = *(const half8*)(&Ws[cout][quad * 8]);
        half8 b1 = *(const half8*)(&Ws[cout][32 + quad * 8]);
        floatx4 acc = {bias, bias, bias, bias};
        acc = __builtin_amdgcn_mfma_f32_16x16x32_f16(ax[0], b0, acc, 0, 0, 0);
        acc = __builtin_amdgcn_mfma_f32_16x16x32_f16(ax[1], b1, acc, 0, 0, 0);
        if (ct < 4) {
            // transposed store: one half4 of 4 consecutive pixels
            half4 vp = {(f16)acc[0], (f16)acc[1], (f16)acc[2], (f16)acc[3]};
            *(half4*)(&Vst[ct * 16 + n16][wave * 16 + quad * 4]) = vp;
        } else {
            float n2[4];
#pragma unroll
            for (int r = 0; r < 4; ++r) n2[r] = acc[r] * acc[r];
#pragma unroll
            for (int d = 1; d < 8; d <<= 1)
#pragma unroll
                for (int r = 0; r < 4; ++r) n2[r] += __shfl_xor(n2[r], d, 64);
            if (n16 == 0) {
#pragma unroll
                for (int r = 0; r < 4; ++r) qn2[p0 + quad * 4 + r] = n2[r];
            }
            // fused per-batch key max: lanes n16>=8 hold kn2 sums
            float km = fmaxf(fmaxf(n2[0], n2[1]), fmaxf(n2[2], n2[3]));
            km = fmaxf(km, __shfl_xor(km, 16, 64));
            km = fmaxf(km, __shfl_xor(km, 32, 64));
            if (n16 == 8) redK[wave] = km;
            if (n16 < 8) {
                f16* dst = Qh + (p0 + quad * 4) * 8 + n16;
#pragma unroll
                for (int r = 0; r < 4; ++r) dst[r * 8] = (f16)acc[r];
            } else {
#pragma unroll
                for (int r = 0; r < 4; ++r)
                    Ks[wave * 16 + quad * 4 + r][n16 - 8] = (f16)acc[r];
            }
        }
    }
    __syncthreads();

    // per-block key-max slot (plain store — no init dispatch needed)
    if (tid == 0) {
        float m = fmaxf(fmaxf(redK[0], redK[1]), fmaxf(redK[2], redK[3]));
        Mkb[blockIdx.x] = m;
    }

    // V fragment stores (2 tiles per wave): gather = two half4 reads from Vst
#pragma unroll
    for (int u = 0; u < 2; ++u) {
        const int tt = wave * 2 + u;
        const int kb = tt >> 2, ct = tt & 3;
        half4 lo = *(const half4*)(&Vst[ct * 16 + n16][kb * 32 + quad * 4]);
        half4 hi = *(const half4*)(&Vst[ct * 16 + n16][kb * 32 + 16 + quad * 4]);
        half8 v = {lo[0], lo[1], lo[2], lo[3], hi[0], hi[1], hi[2], hi[3]};
        const size_t kbg = (size_t)b * 128 + (nnb >> 5) + kb;
        *(half8*)(Vf + (kbg * 4 + ct) * 512 + lane * 8) = v;
    }
    // K pair-tile stores: waves 0-1 each store one pair as full 16B/lane lines
    if (wave < 2) {
        half8 kp = {0, 0, 0, 0, 0, 0, 0, 0};
#pragma unroll
        for (int e = 0; e < 2; ++e) {
            const int t = wave * 2 + e;
            if (quad < 2) {
                half4 kd = *(const half4*)(&Ks[t * 16 + n16][quad * 4]);
                kp[e * 4 + 0] = kd[0]; kp[e * 4 + 1] = kd[1];
                kp[e * 4 + 2] = kd[2]; kp[e * 4 + 3] = kd[3];
            } else if (quad == 2) {
                kp[e * 4 + 0] = (f16)1.f;  // mf ones channel
            }
        }
        const size_t kpg = (size_t)b * 128 + (nnb >> 5) + wave;
        *(half8*)(Kf + kpg * 512 + lane * 8) = kp;
    }
}

// ---------------- flash attention, static-max, 32 q/wave, key-split 4 ----------------
// R16 body verbatim (best measured: 49.6us). grid B*128 = 1024 x 256 thr;
// wave = ks (0..3): keys [ks*1024,+1024), 16 iters of 64 keys. P never
// touches LDS (16x16x16 PV, B = pack4(sf)).
__global__ __launch_bounds__(256, 3) void attn_kernel(
    const f16* __restrict__ Qh, const f16* __restrict__ Kf,
    const f16* __restrict__ Vf,
    const float* __restrict__ qn2, const float* __restrict__ Mkb,
    const float* __restrict__ x, const float* __restrict__ gptr,
    float* __restrict__ out)
{
    // smem: Obuf only (f32, stride 20, 3 partial ks x 2 qt2 x 64 lanes x 16ch)
    __shared__ alignas(16) char smem[30720];
    __shared__ float Ls[4][2][16];
    float* Obuf = (float*)smem;

    const int tid  = threadIdx.x;
    const int wave = tid >> 6, lane = tid & 63;
    const int quad = lane >> 4, n16 = lane & 15;
    const int ks = wave;

    const int b  = blockIdx.x & 7;
    const int qt = blockIdx.x >> 3;               // 0..127 (32-query tile)
    const size_t bN = (size_t)b * NN;

    // per-batch key-norm max: reduce this batch's 64 per-proj-block slots
    float mk2;
    {
        float m = Mkb[b * 64 + lane];             // lanes 0..63 cover all slots
        m = fmaxf(m, __shfl_xor(m, 1, 64));
        m = fmaxf(m, __shfl_xor(m, 2, 64));
        m = fmaxf(m, __shfl_xor(m, 4, 64));
        m = fmaxf(m, __shfl_xor(m, 8, 64));
        m = fmaxf(m, __shfl_xor(m, 16, 64));
        m = fmaxf(m, __shfl_xor(m, 32, 64));
        mk2 = m;
    }

    // Q B-frags: quads 0-1 = Q data; quad2 = {-mf,0,0,0}; quad3 = 0.
    half4 bq4[2];
#pragma unroll
    for (int qt2 = 0; qt2 < 2; ++qt2) {
        const int q = qt * 32 + qt2 * 16 + n16;
        const float mf = __builtin_sqrtf(qn2[bN + q] * mk2) - 12.0f;
        half4 v = {0, 0, 0, 0};
        if (quad < 2)
            v = *(const half4*)(Qh + (bN + q) * 8 + quad * 4);
        else if (quad == 2)
            v[0] = (f16)(-mf);
        bq4[qt2] = v;
    }

    floatx4 oacc[2][4];
#pragma unroll
    for (int qt2 = 0; qt2 < 2; ++qt2)
#pragma unroll
        for (int ct = 0; ct < 4; ++ct) oacc[qt2][ct] = (floatx4){0.f, 0.f, 0.f, 0.f};
    float l_loc[2] = {0.f, 0.f};

    const f16* kfb = Kf + ((size_t)b * 128 + ks * 32) * 512 + lane * 8;
    const f16* vfb = Vf + ((size_t)b * 128 + ks * 32) * 2048 + lane * 8;
    const floatx4 zero4 = {0.f, 0.f, 0.f, 0.f};

    half8 kkc0 = *(const half8*)(kfb + 0);
    half8 kkc1 = *(const half8*)(kfb + 512);

    for (int it = 0; it < 16; ++it) {
        // V A-frag pair loads for this iteration's 64 keys (2 pairs x 4 ct)
        half8 avp[2][4];
#pragma unroll
        for (int p = 0; p < 2; ++p)
#pragma unroll
            for (int ct = 0; ct < 4; ++ct)
                avp[p][ct] = *(const half8*)(vfb + ((size_t)(it * 2 + p) * 4 + ct) * 512);

        half4 ak[4];
        ak[0] = __builtin_shufflevector(kkc0, kkc0, 0, 1, 2, 3);
        ak[1] = __builtin_shufflevector(kkc0, kkc0, 4, 5, 6, 7);
        ak[2] = __builtin_shufflevector(kkc1, kkc1, 0, 1, 2, 3);
        ak[3] = __builtin_shufflevector(kkc1, kkc1, 4, 5, 6, 7);

        // prefetch kk(it+1)
        const int itn = (it < 15) ? it + 1 : 15;
        kkc0 = *(const half8*)(kfb + (size_t)itn * 1024);
        kkc1 = *(const half8*)(kfb + (size_t)itn * 1024 + 512);

#pragma unroll
        for (int qt2 = 0; qt2 < 2; ++qt2) {
            floatx4 sf[4];
#pragma unroll
            for (int t = 0; t < 4; ++t)
                sf[t] = __builtin_amdgcn_mfma_f32_16x16x16f16(ak[t], bq4[qt2], zero4, 0, 0, 0);

            half4 pk[4];
            float rst[4];
#pragma unroll
            for (int t = 0; t < 4; ++t) {
                float p0 = __builtin_exp2f(sf[t][0]);
                float p1 = __builtin_exp2f(sf[t][1]);
                float p2 = __builtin_exp2f(sf[t][2]);
                float p3 = __builtin_exp2f(sf[t][3]);
                rst[t] = (p0 + p1) + (p2 + p3);
                pk[t] = pack4(p0, p1, p2, p3);
            }
            l_loc[qt2] += (rst[0] + rst[1]) + (rst[2] + rst[3]);

            // PV: 16x16x16, A = V tile frag (even/odd half of pair), B = pk[t]
#pragma unroll
            for (int t = 0; t < 4; ++t) {
                const int p = t >> 1;
#pragma unroll
                for (int ct = 0; ct < 4; ++ct) {
                    half4 va = (t & 1)
                        ? __builtin_shufflevector(avp[p][ct], avp[p][ct], 4, 5, 6, 7)
                        : __builtin_shufflevector(avp[p][ct], avp[p][ct], 0, 1, 2, 3);
                    oacc[qt2][ct] = __builtin_amdgcn_mfma_f32_16x16x16f16(va, pk[t], oacc[qt2][ct], 0, 0, 0);
                }
            }
        }
    }

    float l_run[2];
#pragma unroll
    for (int qt2 = 0; qt2 < 2; ++qt2) {
        float l = l_loc[qt2];
        l += __shfl_xor(l, 16, 64);
        l += __shfl_xor(l, 32, 64);
        l_run[qt2] = l;
    }

    __syncthreads();   // Obuf combine (f32, stride 20)
    if (ks > 0) {
#pragma unroll
        for (int qt2 = 0; qt2 < 2; ++qt2) {
            if (quad == 0) Ls[ks][qt2][n16] = l_run[qt2];
            float* ob = Obuf + (size_t)(((ks - 1) * 2 + qt2) * 64 + lane) * 20;
#pragma unroll
            for (int ct = 0; ct < 4; ++ct)
                *(floatx4*)(ob + ct * 4) = oacc[qt2][ct];
        }
    }
    __syncthreads();
    if (ks == 0) {
        const float g = gptr[0];
#pragma unroll
        for (int qt2 = 0; qt2 < 2; ++qt2) {
            float l = l_run[qt2];
            float o[16];
#pragma unroll
            for (int ct = 0; ct < 4; ++ct)
#pragma unroll
                for (int r = 0; r < 4; ++r) o[ct * 4 + r] = oacc[qt2][ct][r];
#pragma unroll
            for (int p = 1; p < 4; ++p) {
                l += Ls[p][qt2][n16];
                const float* ob = Obuf + (size_t)(((p - 1) * 2 + qt2) * 64 + lane) * 20;
#pragma unroll
                for (int ct = 0; ct < 4; ++ct) {
                    floatx4 t = *(const floatx4*)(ob + ct * 4);
                    o[ct * 4 + 0] += t[0]; o[ct * 4 + 1] += t[1];
                    o[ct * 4 + 2] += t[2]; o[ct * 4 + 3] += t[3];
                }
            }
            const float scale = g / l;
            const int q = qt * 32 + qt2 * 16 + n16;
#pragma unroll
            for (int ct = 0; ct < 4; ++ct) {
                const size_t idx = (bN + q) * CC + ct * 16 + quad * 4;
                float4 xr = *(const float4*)(x + idx);
                float4 res;
                res.x = o[ct * 4 + 0] * scale + xr.x;
                res.y = o[ct * 4 + 1] * scale + xr.y;
                res.z = o[ct * 4 + 2] * scale + xr.z;
                res.w = o[ct * 4 + 3] * scale + xr.w;
                *(float4*)(out + idx) = res;
            }
        }
    }
}

extern "C" void kernel_launch(void* const* d_in, const int* in_sizes, int n_in,
                              void* d_out, int out_size, void* d_ws, size_t ws_size,
                              hipStream_t stream) {
    const float* x     = (const float*)d_in[0];
    const float* wq    = (const float*)d_in[1];
    const float* bq    = (const float*)d_in[2];
    const float* wk    = (const float*)d_in[3];
    const float* bk    = (const float*)d_in[4];
    const float* wv    = (const float*)d_in[5];
    const float* bv    = (const float*)d_in[6];
    const float* gamma = (const float*)d_in[7];
    float* out = (float*)d_out;

    // ws: Qh 512KB | Kf 1MB | Vf 4MB | qn2 128KB | Mkb 2KB (per-block maxima)
    f16* Qh = (f16*)d_ws;
    f16* Kf = Qh + (size_t)BB * NN * 8;
    f16* Vf = Kf + (size_t)BB * 128 * 512;
    float* qn2 = (float*)(Vf + (size_t)BB * 128 * 4 * 512);
    float* Mkb = qn2 + (size_t)BB * NN;

    proj_all_kernel<<<512, 256, 0, stream>>>(x, wq, bq, wk, bk, wv, bv,
                                             Qh, Kf, Vf, qn2, Mkb);
    attn_kernel<<<BB * 128, 256, 0, stream>>>(Qh, Kf, Vf, qn2, Mkb, x, gamma, out);
}